// Round 1
// 2398.352 us; speedup vs baseline: 1.3632x; 1.3632x over previous
//
#include <hip/hip_runtime.h>
#include <hip/hip_fp16.h>
#include <math.h>

#define TID ((int)threadIdx.x)

// dims: V=30000 K=50 E=300 T=60 B=128 TH=800 H=200 L=3
// beta GEMM tiling: NVB=235 v-blocks of 128 rows (30080 padded), t-split 4 x 15
#define NVB 235

static __device__ __forceinline__ float sigf(float x){ return 1.f/(1.f+expf(-x)); }

static __device__ __forceinline__ unsigned short f2bf(float f){
  unsigned u = __float_as_uint(f);
  unsigned r = (u + 0x7FFFu + ((u>>16)&1u)) >> 16;
  return (unsigned short)r;
}

typedef short v8ss __attribute__((ext_vector_type(8)));
typedef float v16f __attribute__((ext_vector_type(16)));
union I4BF { int4 i; v8ss s; };
union U16B { int4 i; __half2 h2[4]; };

#define REP25(M) M(0) M(1) M(2) M(3) M(4) M(5) M(6) M(7) M(8) M(9) M(10) M(11) \
                 M(12) M(13) M(14) M(15) M(16) M(17) M(18) M(19) M(20) M(21) M(22) M(23) M(24)

#define DECLW(n) int4 w##n = wrow[n];
#define DOTW(n) { U16B u; u.i = w##n; \
    float4 hA = hs4[2*(n)], hB = hs4[2*(n)+1]; \
    float2 q0=__half22float2(u.h2[0]), q1=__half22float2(u.h2[1]); \
    float2 q2=__half22float2(u.h2[2]), q3=__half22float2(u.h2[3]); \
    a0=fmaf(q0.x,hA.x,a0); a1=fmaf(q0.y,hA.y,a1); \
    a2=fmaf(q1.x,hA.z,a2); a3=fmaf(q1.y,hA.w,a3); \
    a0=fmaf(q2.x,hB.x,a0); a1=fmaf(q2.y,hB.y,a1); \
    a2=fmaf(q3.x,hB.z,a2); a3=fmaf(q3.y,hB.w,a3); }

// ---------------- init ----------------
__global__ void k_zero(float* acc, int* flags){
  if (TID<8) acc[TID]=0.f;
  if (TID<128) flags[TID]=0;
}

// ---------------- alphas + kl_alpha ----------------
__global__ void k_alphas(const float* __restrict__ mqa, const float* __restrict__ lqa,
                         const float* __restrict__ eps, float* __restrict__ alphas){
  int i = blockIdx.x*256+TID; if (i>=900000) return;
  int t = i/15000, r = i%15000, k = r/300, e = r%300;
  int src = k*18000 + t*300 + e;
  float mu = mqa[src], ls = lqa[src];
  alphas[i] = mu + eps[i]*expf(0.5f*ls);
}

__global__ void k_klalpha(const float* __restrict__ mqa, const float* __restrict__ lqa,
                          const float* __restrict__ alphas, float* acc){
  __shared__ float red[256];
  int i = blockIdx.x*256+TID;
  float term = 0.f;
  if (i<900000){
    int t = i/15000, r = i%15000, k = r/300, e = r%300;
    int src = k*18000 + t*300 + e;
    float mu = mqa[src], ls = lqa[src];
    if (t==0){
      term = (expf(ls)+mu*mu)*(1.0f/(1.0f+1e-6f)) - 1.f - ls;
    } else {
      float d = mu - alphas[i-15000];
      term = (expf(ls)+d*d)*(1.0f/(0.005f+1e-6f)) - 1.f + logf(0.005f) - ls;
    }
  }
  red[TID]=term; __syncthreads();
  for (int s=128;s>0;s>>=1){ if (TID<s) red[TID]+=red[TID+s]; __syncthreads(); }
  if (TID==0) atomicAdd(acc+0, 0.5f*red[0]);
}

// ---------------- bf16 fragment prep for beta GEMM ----------------
__global__ void k_prep_rho(const float* __restrict__ rho, unsigned short* __restrict__ rho_f){
  int tid = blockIdx.x*256+TID;
  if (tid >= 940*19*64) return;
  int lane = tid & 63;
  int F = tid >> 6;
  int kstep = F % 19;
  int r32 = F / 19;
  int v = r32*32 + (lane & 31);
  int e0 = kstep*16 + ((lane>>5)<<3);
  unsigned short u[8];
  #pragma unroll
  for (int j=0;j<8;j++){
    int e = e0 + j;
    float val = (v < 30000 && e < 300) ? rho[v*300 + e] : 0.f;
    u[j] = f2bf(val);
  }
  int4 o;
  o.x = (int)u[0] | ((int)u[1]<<16);
  o.y = (int)u[2] | ((int)u[3]<<16);
  o.z = (int)u[4] | ((int)u[5]<<16);
  o.w = (int)u[6] | ((int)u[7]<<16);
  ((int4*)rho_f)[tid] = o;
}

__global__ void k_prep_alpha(const float* __restrict__ alphas, unsigned short* __restrict__ alpha_f){
  int tid = blockIdx.x*256+TID;
  if (tid >= 60*2*19*64) return;
  int lane = tid & 63;
  int F = tid >> 6;
  int kstep = F % 19;
  int tn = F / 19;
  int nt = tn % 2, t = tn / 2;
  int k = nt*32 + (lane & 31);
  int e0 = kstep*16 + ((lane>>5)<<3);
  unsigned short u[8];
  #pragma unroll
  for (int j=0;j<8;j++){
    int e = e0 + j;
    float val = (k < 50 && e < 300) ? alphas[t*15000 + k*300 + e] : 0.f;
    u[j] = f2bf(val);
  }
  int4 o;
  o.x = (int)u[0] | ((int)u[1]<<16);
  o.y = (int)u[2] | ((int)u[3]<<16);
  o.z = (int)u[4] | ((int)u[5]<<16);
  o.w = (int)u[6] | ((int)u[7]<<16);
  ((int4*)alpha_f)[tid] = o;
}

// ---------------- Whh + Wih f32 -> f16 (3 layers, 480000 elems each) ----------------
__global__ void k_prep_w16(const float* __restrict__ Whh, const float* __restrict__ Wih,
                           __half* __restrict__ WhhH, __half* __restrict__ WihH){
  int i = blockIdx.x*256+TID;
  if (i<480000){
    WhhH[i] = __float2half_rn(Whh[i]);
    WihH[i] = __float2half_rn(Wih[i]);
  }
}

// ---------------- inp_map = rnn_inp @ Wmap.T + bmap ----------------
__global__ void k_iminit(float* __restrict__ im, const float* __restrict__ bmap){
  int i = blockIdx.x*256+TID; if (i<12000) im[i] = bmap[i%200];
}

// tiled: block = (hb: 32 h-rows, kb: 500 k). Wmap tile in LDS (64KB), rnn slice
// staged per t. 8 lanes per h row, float2 LDS dots, shfl-reduce, 1 atomic.
__global__ __launch_bounds__(256,2) void k_imgemm(const float* __restrict__ rnn,
        const float* __restrict__ Wmap, float* __restrict__ im){
  __shared__ __align__(16) float Ws[32*500];
  __shared__ __align__(16) float rnS[500];
  int hb = blockIdx.x;       // 0..6
  int kb = blockIdx.y;       // 0..59
  int h0 = hb*32;
  int nh = (h0+32<=200)?32:(200-h0);
  const int kbase = kb*500;
  for (int i=TID; i<nh*125; i+=256){
    int h = i/125, q = i%125;
    *reinterpret_cast<float4*>(&Ws[h*500 + q*4]) =
      *reinterpret_cast<const float4*>(&Wmap[(h0+h)*30000 + kbase + q*4]);
  }
  int h = TID>>3, sub = TID&7;
  bool act = (h < nh);
  __syncthreads();
  for (int t=0;t<60;t++){
    if (TID<125)
      *reinterpret_cast<float4*>(&rnS[TID*4]) =
        *reinterpret_cast<const float4*>(&rnn[t*30000 + kbase + TID*4]);
    __syncthreads();
    float a = 0.f;
    if (act){
      const float2* wp = reinterpret_cast<const float2*>(&Ws[h*500]);
      const float2* rp = reinterpret_cast<const float2*>(rnS);
      for (int k2=sub;k2<250;k2+=8){
        float2 wv=wp[k2], rv=rp[k2];
        a = fmaf(wv.x,rv.x,a); a = fmaf(wv.y,rv.y,a);
      }
    }
    a += __shfl_down(a,4); a += __shfl_down(a,2); a += __shfl_down(a,1);
    if (act && sub==0) atomicAdd(&im[t*200 + h0 + h], a);
    __syncthreads();
  }
}

// ---------------- LSTM pre-gates (layer 0 only; input fully known) ----------------
__global__ void k_pregates(const float* __restrict__ x, const float* __restrict__ Wih,
                           const float* __restrict__ bih, const float* __restrict__ bhh,
                           float* __restrict__ pre){
  __shared__ float xS[200];
  int t = blockIdx.x;
  if (TID<200) xS[TID] = x[t*200+TID];
  __syncthreads();
  int r = blockIdx.y*256 + TID;
  if (r>=800) return;
  float a = bih[r] + bhh[r];
  const float* wp = Wih + r*200;
  #pragma unroll 4
  for (int c=0;c<200;c++) a = fmaf(wp[c], xS[c], a);
  pre[t*800+r] = a;
}

// ---------------- pipelined LSTM: 5 blocks = rec0 -> gemv1 -> rec1 -> gemv2 -> rec2 ----
// Cross-block handoff per timestep via agent-scope release/acquire flags (blocks land
// on different XCDs; device-scope required per CDNA4 non-coherent L2s).

static __device__ __forceinline__ void pipe_wait(int* flag, int val){
  if (TID==0){
    while (__hip_atomic_load(flag, __ATOMIC_ACQUIRE, __HIP_MEMORY_SCOPE_AGENT) < val)
      __builtin_amdgcn_s_sleep(2);
  }
  __syncthreads();
}

static __device__ __forceinline__ void pipe_post(int* flag, int val){
  // caller guarantees a __syncthreads() (vmcnt-drained per wave) precedes this
  if (TID==0)
    __hip_atomic_store(flag, val, __ATOMIC_RELEASE, __HIP_MEMORY_SCOPE_AGENT);
}

// recurrent cell chain: weights in 25 named int4 regs (f16), rows 768-799 via LDS tail
static __device__ __forceinline__ void lstm_rec(const float* __restrict__ pre,
    const __half* __restrict__ WhhH, float* __restrict__ out,
    int* inFlag, int* outFlag)
{
  __shared__ __align__(16) float hsF[200];
  __shared__ float gsh[800];
  __shared__ __half wtH[32*200];
  for (int i=TID;i<6400;i+=768) wtH[i] = WhhH[768*200 + i];
  const int4* wrow = reinterpret_cast<const int4*>(WhhH + TID*200);
  REP25(DECLW)
  float c_reg = 0.f;
  if (TID<200) hsF[TID]=0.f;
  int j = TID - 512;
  int trow = (j>=0) ? (j>>3) : 0;
  int tseg = (j>=0) ? (j&7)*25 : 0;
  __syncthreads();
  for (int t=0;t<60;t++){
    if (inFlag) pipe_wait(inFlag, t+1);
    float p = pre[t*800+TID];          // latency hides under the h-dot below
    float a0=0.f,a1=0.f,a2=0.f,a3=0.f;
    const float4* hs4 = reinterpret_cast<const float4*>(hsF);
    REP25(DOTW)
    gsh[TID] = a0+a1+a2+a3 + p;
    if (j>=0){
      float pa = 0.f;
      const __half* wt = &wtH[trow*200 + tseg];
      const float* hp = &hsF[tseg];
      #pragma unroll
      for (int c2=0;c2<25;c2++) pa = fmaf(__half2float(wt[c2]), hp[c2], pa);
      pa += __shfl_down(pa,4); pa += __shfl_down(pa,2); pa += __shfl_down(pa,1);
      if ((j&7)==0) gsh[768+trow] = pa + pre[t*800+768+trow];
    }
    __syncthreads();
    if (TID<200){
      float ii=gsh[TID], ff=gsh[200+TID], gg=gsh[400+TID], oo=gsh[600+TID];
      float c = sigf(ff)*c_reg + sigf(ii)*tanhf(gg);
      c_reg = c;
      float h = sigf(oo)*tanhf(c);
      hsF[TID]=h;
      out[t*200+TID]=h;
    }
    __syncthreads();
    if (outFlag) pipe_post(outFlag, t+1);
  }
}

// input-gemv stage: pre_l[t] = Wih_l @ out_{l-1}[t] + bih + bhh
static __device__ __forceinline__ void lstm_gemv(const float* __restrict__ xIn,
    const __half* __restrict__ WH, const float* __restrict__ bih,
    const float* __restrict__ bhh, float* __restrict__ preOut,
    int* inFlag, int* outFlag)
{
  __shared__ __align__(16) float xS[200];
  __shared__ __half wtG[32*200];
  for (int i=TID;i<6400;i+=768) wtG[i] = WH[768*200 + i];
  const int4* wrow = reinterpret_cast<const int4*>(WH + TID*200);
  REP25(DECLW)
  float bb = bih[TID] + bhh[TID];
  int j = TID - 512;
  int trow = (j>=0) ? (j>>3) : 0;
  int tseg = (j>=0) ? (j&7)*25 : 0;
  float bbT = 0.f;
  if (j>=0 && (j&7)==0) bbT = bih[768+trow] + bhh[768+trow];
  for (int t=0;t<60;t++){
    pipe_wait(inFlag, t+1);
    if (TID<200) xS[TID] = xIn[t*200+TID];
    __syncthreads();
    float a0=0.f,a1=0.f,a2=0.f,a3=0.f;
    const float4* hs4 = reinterpret_cast<const float4*>(xS);
    REP25(DOTW)
    preOut[t*800+TID] = a0+a1+a2+a3 + bb;
    if (j>=0){
      float pa = 0.f;
      const __half* wt = &wtG[trow*200 + tseg];
      const float* hp = &xS[tseg];
      #pragma unroll
      for (int c2=0;c2<25;c2++) pa = fmaf(__half2float(wt[c2]), hp[c2], pa);
      pa += __shfl_down(pa,4); pa += __shfl_down(pa,2); pa += __shfl_down(pa,1);
      if ((j&7)==0) preOut[t*800+768+trow] = pa + bbT;
    }
    __syncthreads();
    pipe_post(outFlag, t+1);
  }
}

__global__ __launch_bounds__(768,3) void k_lstm_pipe(const float* __restrict__ pre0,
    const __half* __restrict__ WhhH, const __half* __restrict__ WihH,
    const float* __restrict__ bih, const float* __restrict__ bhh,
    float* __restrict__ out0, float* __restrict__ out1, float* __restrict__ out2,
    float* __restrict__ pre1, float* __restrict__ pre2, int* __restrict__ flags)
{
  switch (blockIdx.x){
    case 0: lstm_rec (pre0, WhhH,         out0, nullptr,  flags+0);  break;
    case 1: lstm_gemv(out0, WihH+160000, bih+800,  bhh+800,  pre1, flags+0,  flags+32); break;
    case 2: lstm_rec (pre1, WhhH+160000,  out1, flags+32, flags+64); break;
    case 3: lstm_gemv(out1, WihH+320000, bih+1600, bhh+1600, pre2, flags+64, flags+96); break;
    default: lstm_rec(pre2, WhhH+320000,  out2, flags+96, nullptr);  break;
  }
}

// ---------------- eta chain (single block) ----------------
__global__ void k_eta(const float* __restrict__ outF, const float* __restrict__ Wmu,
                      const float* __restrict__ bmu, const float* __restrict__ Wls,
                      const float* __restrict__ bls, const float* __restrict__ eps,
                      float* __restrict__ etas, float* acc){
  __shared__ __half wS[100*254];
  __shared__ float inp[256];
  __shared__ float pt[200];
  __shared__ float muS[64], lsS[64];
  for (int i=TID;i<12500;i+=256) wS[(i/250)*254 + (i%250)] = __float2half_rn(Wmu[i]);
  for (int i=TID;i<12500;i+=256) wS[(50+i/250)*254 + (i%250)] = __float2half_rn(Wls[i]);
  if (TID<50) inp[200+TID]=0.f;
  const float LOGD = logf(0.005f);
  float kacc = 0.f;
  __syncthreads();
  for (int t=0;t<60;t++){
    if (TID<200) inp[TID] = outF[t*200+TID];
    __syncthreads();
    if (TID<200){
      int rr = TID%100, hf = TID/100;
      const __half* wp = &wS[rr*254 + hf*125];
      const float* ip = &inp[hf*125];
      float s=0.f;
      for (int c=0;c<125;c++) s = fmaf(__half2float(wp[c]), ip[c], s);
      pt[TID]=s;
    }
    __syncthreads();
    if (TID<100){
      float v = pt[TID]+pt[TID+100];
      if (TID<50) muS[TID] = v + bmu[TID];
      else lsS[TID-50] = v + bls[TID-50];
    }
    __syncthreads();
    if (TID<64){
      float term=0.f;
      if (TID<50){
        float mu=muS[TID], ls=lsS[TID], ep=inp[200+TID];
        if (t==0) term = (expf(ls)+mu*mu)*(1.0f/(1.0f+1e-6f)) - 1.f - ls;
        else { float d=mu-ep; term = (expf(ls)+d*d)*(1.0f/(0.005f+1e-6f)) - 1.f + LOGD - ls; }
        float et = mu + eps[t*50+TID]*expf(0.5f*ls);
        etas[t*50+TID]=et;
        inp[200+TID]=et;
      }
      for (int o=32;o>0;o>>=1) term += __shfl_down(term,o);
      if (TID==0) kacc += 0.5f*term;
    }
    __syncthreads();
  }
  if (TID==0) atomicAdd(acc+1, kacc);
}

// ---------------- h1 = qt_in @ W1.T + b1 (atomic k-split GEMM) ----------------
__global__ void k_h1init(float* __restrict__ h1, const float* __restrict__ b1){
  int i = blockIdx.x*256+TID; if (i<102400) h1[i] = b1[i%800];
}

__global__ void k_h1gemm(const float* __restrict__ nb, const int* __restrict__ times,
                         const float* __restrict__ etas, const float* __restrict__ W1,
                         float* __restrict__ h1){
  __shared__ __align__(16) float As[16*132];
  __shared__ __align__(16) float Ws[16*68];
  __shared__ int tS[128];
  if (TID<128) tS[TID]=times[TID];
  int rt = blockIdx.x, sp = blockIdx.y;
  int kbeg = sp*940;
  int kend = (kbeg+940<30050)?(kbeg+940):30050;
  int b0 = (TID%32)*4, r0 = (TID/32)*8;
  float acc[32];
  #pragma unroll
  for (int j=0;j<32;j++) acc[j]=0.f;
  for (int kb=kbeg; kb<kend; kb+=16){
    __syncthreads();
    for (int i=TID;i<2048;i+=256){
      int b=i/16, kk=i%16, kg=kb+kk;
      float v=0.f;
      if (kg<kend){ v = (kg<30000)? nb[b*30000+kg] : etas[tS[b]*50 + (kg-30000)]; }
      As[kk*132+b]=v;
    }
    for (int i=TID;i<1024;i+=256){
      int r=i/16, kk=i%16, kg=kb+kk, rg=rt*64+r;
      float v=0.f;
      if (kg<kend && rg<800) v = W1[rg*30050+kg];
      Ws[kk*68+r]=v;
    }
    __syncthreads();
    #pragma unroll
    for (int kk=0;kk<16;kk++){
      float4 a4 = *reinterpret_cast<const float4*>(&As[kk*132+b0]);
      float4 w4 = *reinterpret_cast<const float4*>(&Ws[kk*68+r0]);
      float4 w5 = *reinterpret_cast<const float4*>(&Ws[kk*68+r0+4]);
      float aa[4]={a4.x,a4.y,a4.z,a4.w};
      float ww[8]={w4.x,w4.y,w4.z,w4.w,w5.x,w5.y,w5.z,w5.w};
      #pragma unroll
      for (int j=0;j<4;j++)
        #pragma unroll
        for (int i2=0;i2<8;i2++) acc[j*8+i2] = fmaf(aa[j], ww[i2], acc[j*8+i2]);
    }
  }
  #pragma unroll
  for (int j=0;j<4;j++){
    int b=b0+j;
    #pragma unroll
    for (int i2=0;i2<8;i2++){
      int rg = rt*64+r0+i2;
      if (rg<800) atomicAdd(&h1[b*800+rg], acc[j*8+i2]);
    }
  }
}

// ---------------- h2 = relu(relu(h1) @ W2.T + b2), tiled 32x64 ----------------
__global__ __launch_bounds__(256) void k_h2(const float* __restrict__ h1,
        const float* __restrict__ W2, const float* __restrict__ b2,
        float* __restrict__ h2){
  __shared__ __align__(16) float As[16*33];
  __shared__ __align__(16) float Ws[16*68];
  int bt = blockIdx.x;  // 0..3  (32 docs)
  int rt = blockIdx.y;  // 0..12 (64 rows)
  int b0 = (TID%16)*2, r0 = (TID/16)*4;
  float acc[8] = {0,0,0,0,0,0,0,0};
  for (int kb=0; kb<800; kb+=16){
    __syncthreads();
    for (int i=TID;i<512;i+=256){
      int b=i>>4, k=i&15;
      As[k*33+b] = fmaxf(h1[(bt*32+b)*800 + kb + k], 0.f);
    }
    for (int i=TID;i<1024;i+=256){
      int r=i>>4, k=i&15; int rg = rt*64+r;
      Ws[k*68+r] = (rg<800) ? W2[rg*800 + kb + k] : 0.f;
    }
    __syncthreads();
    #pragma unroll
    for (int k=0;k<16;k++){
      float a0=As[k*33+b0], a1=As[k*33+b0+1];
      float4 w4 = *reinterpret_cast<const float4*>(&Ws[k*68+r0]);
      acc[0]=fmaf(a0,w4.x,acc[0]); acc[1]=fmaf(a0,w4.y,acc[1]);
      acc[2]=fmaf(a0,w4.z,acc[2]); acc[3]=fmaf(a0,w4.w,acc[3]);
      acc[4]=fmaf(a1,w4.x,acc[4]); acc[5]=fmaf(a1,w4.y,acc[5]);
      acc[6]=fmaf(a1,w4.z,acc[6]); acc[7]=fmaf(a1,w4.w,acc[7]);
    }
  }
  #pragma unroll
  for (int jj=0;jj<2;jj++){
    int b = bt*32 + b0 + jj;
    #pragma unroll
    for (int i2=0;i2<4;i2++){
      int rg = rt*64 + r0 + i2;
      if (rg<800) h2[b*800+rg] = fmaxf(acc[jj*4+i2] + b2[rg], 0.f);
    }
  }
}

// ---------------- mu_th / ls_th ----------------
__global__ void k_muls(const float* __restrict__ h2, const float* __restrict__ Wmu,
                       const float* __restrict__ bmu, const float* __restrict__ Wls,
                       const float* __restrict__ bls, float* __restrict__ muth,
                       float* __restrict__ lsth){
  __shared__ float hS[800];
  int b = blockIdx.x;
  for (int i=TID;i<800;i+=128) hS[i] = h2[b*800+i];
  __syncthreads();
  if (TID<50){
    float a = bmu[TID];
    const float* wp = Wmu + TID*800;
    #pragma unroll 4
    for (int c=0;c<800;c++) a = fmaf(wp[c], hS[c], a);
    muth[b*50+TID]=a;
  } else if (TID>=64 && TID<114){
    int r = TID-64;
    float a = bls[r];
    const float* wp = Wls + r*800;
    #pragma unroll 4
    for (int c=0;c<800;c++) a = fmaf(wp[c], hS[c], a);
    lsth[b*50+r]=a;
  }
}

// ---------------- theta + kl_theta ----------------
__global__ void k_theta(const float* __restrict__ muth, const float* __restrict__ lsth,
                        const float* __restrict__ etas, const int* __restrict__ times,
                        const float* __restrict__ epsth, float* __restrict__ theta,
                        float* acc){
  int b = blockIdx.x, k = TID;
  bool a = k<50;
  int tb = times[b];
  float mu=0.f, ls=0.f, etd=0.f, z=-INFINITY;
  if (a){
    mu = muth[b*50+k]; ls = lsth[b*50+k]; etd = etas[tb*50+k];
    z = mu + epsth[b*50+k]*expf(0.5f*ls);
  }
  float m=z;
  for (int o=32;o>0;o>>=1) m = fmaxf(m, __shfl_xor(m,o));
  float e = a ? expf(z-m) : 0.f;
  float s = e;
  for (int o=32;o>0;o>>=1) s += __shfl_xor(s,o);
  if (a) theta[b*50+k] = e/s;
  float term = a ? ((expf(ls)+(mu-etd)*(mu-etd))*(1.0f/(1.0f+1e-6f)) - 1.f - ls) : 0.f;
  for (int o=32;o>0;o>>=1) term += __shfl_xor(term,o);
  if (TID==0) atomicAdd(acc+2, 0.5f*term);
}

// ---------------- MFMA beta pass 1 ----------------
__global__ __launch_bounds__(256,2) void k_mf1(const unsigned short* __restrict__ rho_f,
        const unsigned short* __restrict__ alpha_f,
        float* __restrict__ Mp, float* __restrict__ Sp){
  int vb = blockIdx.x, tg = blockIdx.y;
  int wid = TID>>6, lane = TID&63;
  int r32 = vb*4 + wid;
  const int4* ap = ((const int4*)rho_f) + (r32*19)*64 + lane;
  int4 a[19];
  #pragma unroll
  for (int ks=0;ks<19;ks++) a[ks] = ap[ks*64];
  __shared__ float redM[4][64];
  __shared__ float redS[4][64];
  int rowbase = vb*128 + wid*32 + ((lane>>5)<<2);
  for (int t = tg*15; t < tg*15+15; t++){
    v16f acc0, acc1;
    #pragma unroll
    for (int i=0;i<16;i++){ acc0[i]=0.f; acc1[i]=0.f; }
    const int4* bp = ((const int4*)alpha_f) + (t*38)*64 + lane;
    #pragma unroll
    for (int ks=0;ks<19;ks++){
      I4BF av, b0, b1;
      av.i = a[ks];
      b0.i = bp[ks*64];
      b1.i = bp[(19+ks)*64];
      acc0 = __builtin_amdgcn_mfma_f32_32x32x16_bf16(av.s, b0.s, acc0, 0,0,0);
      acc1 = __builtin_amdgcn_mfma_f32_32x32x16_bf16(av.s, b1.s, acc1, 0,0,0);
    }
    float m0=-INFINITY, m1=-INFINITY;
    #pragma unroll
    for (int r=0;r<16;r++){
      int v = rowbase + (r&3) + ((r>>2)<<3);
      if (v < 30000){ m0 = fmaxf(m0, acc0[r]); m1 = fmaxf(m1, acc1[r]); }
    }
    m0 = fmaxf(m0, __shfl_xor(m0, 32));
    m1 = fmaxf(m1, __shfl_xor(m1, 32));
    float s0=0.f, s1=0.f;
    #pragma unroll
    for (int r=0;r<16;r++){
      int v = rowbase + (r&3) + ((r>>2)<<3);
      if (v < 30000){ s0 += expf(acc0[r]-m0); s1 += expf(acc1[r]-m1); }
    }
    s0 += __shfl_xor(s0, 32);
    s1 += __shfl_xor(s1, 32);
    if (lane < 32){
      redM[wid][lane] = m0; redM[wid][lane+32] = m1;
      redS[wid][lane] = s0; redS[wid][lane+32] = s1;
    }
    __syncthreads();
    if (TID < 50){
      float M = redM[0][TID];
      #pragma unroll
      for (int w2=1; w2<4; w2++) M = fmaxf(M, redM[w2][TID]);
      float S = 0.f;
      #pragma unroll
      for (int w2=0; w2<4; w2++){
        float mw = redM[w2][TID];
        if (mw > -INFINITY) S += redS[w2][TID] * expf(mw - M);
      }
      Mp[(t*50+TID)*NVB + vb] = M;
      Sp[(t*50+TID)*NVB + vb] = S;
    }
    __syncthreads();
  }
}

// ---------------- reduce partials -> M, 1/S ----------------
__global__ void k_msred(const float* __restrict__ Mp, const float* __restrict__ Sp,
                        float* __restrict__ Mg, float* __restrict__ iSg){
  __shared__ float red[256];
  int row = blockIdx.x;
  float m = (TID<NVB) ? Mp[row*NVB+TID] : -INFINITY;
  red[TID]=m; __syncthreads();
  for (int s=128;s>0;s>>=1){ if (TID<s) red[TID]=fmaxf(red[TID],red[TID+s]); __syncthreads(); }
  float M = red[0]; __syncthreads();
  float sv = (TID<NVB) ? Sp[row*NVB+TID]*expf(m-M) : 0.f;
  red[TID]=sv; __syncthreads();
  for (int s=128;s>0;s>>=1){ if (TID<s) red[TID]+=red[TID+s]; __syncthreads(); }
  if (TID==0){ Mg[row]=M; iSg[row]=1.f/red[0]; }
}

// ---------------- MFMA beta pass 2: recompute, normalize, fuse nll ----------------
__global__ __launch_bounds__(256,2) void k_mf2(const unsigned short* __restrict__ rho_f,
        const unsigned short* __restrict__ alpha_f,
        const float* __restrict__ Mg, const float* __restrict__ iSg,
        const float* __restrict__ theta, const int* __restrict__ times,
        const float* __restrict__ bows, float* acc){
  __shared__ float thS[128*52];
  __shared__ float tileS[4][32*66];
  __shared__ int tS[128];
  __shared__ int cntS[64];
  int vb = blockIdx.x, tg = blockIdx.y;
  int wid = TID>>6, lane = TID&63;
  if (TID < 64) cntS[TID] = 0;
  __syncthreads();
  if (TID < 128){ int tv = times[TID]; tS[TID] = tv; atomicAdd(&cntS[tv], 1); }
  for (int i=TID; i<6400; i+=256){ int b=i/50, c=i%50; thS[b*52+c] = theta[i]; }
  int r32 = vb*4 + wid;
  const int4* ap = ((const int4*)rho_f) + (r32*19)*64 + lane;
  int4 a[19];
  #pragma unroll
  for (int ks=0;ks<19;ks++) a[ks] = ap[ks*64];
  __syncthreads();
  float local = 0.f;
  int rb32 = ((lane>>5)<<2);
  int c0 = lane&31, c1 = 32 + (lane&31);
  for (int t = tg*15; t < tg*15+15; t++){
    if (cntS[t] == 0) continue;
    v16f acc0, acc1;
    #pragma unroll
    for (int i=0;i<16;i++){ acc0[i]=0.f; acc1[i]=0.f; }
    const int4* bp = ((const int4*)alpha_f) + (t*38)*64 + lane;
    #pragma unroll
    for (int ks=0;ks<19;ks++){
      I4BF av, b0, b1;
      av.i = a[ks];
      b0.i = bp[ks*64];
      b1.i = bp[(19+ks)*64];
      acc0 = __builtin_amdgcn_mfma_f32_32x32x16_bf16(av.s, b0.s, acc0, 0,0,0);
      acc1 = __builtin_amdgcn_mfma_f32_32x32x16_bf16(av.s, b1.s, acc1, 0,0,0);
    }
    float M0 = Mg[t*50+c0], i0 = iSg[t*50+c0];
    float M1 = 0.f, i1 = 0.f;
    if (c1 < 50){ M1 = Mg[t*50+c1]; i1 = iSg[t*50+c1]; }
    float* tl = &tileS[wid][0];
    #pragma unroll
    for (int r=0;r<16;r++){
      int row = rb32 + (r&3) + ((r>>2)<<3);
      tl[row*66 + c0] = expf(acc0[r]-M0)*i0;
      if (c1 < 50) tl[row*66 + c1] = expf(acc1[r]-M1)*i1;
    }
    __syncthreads();
    for (int b=0;b<128;b++){
      if (tS[b] != t) continue;
      int row = lane&31;
      int v = vb*128 + wid*32 + row;
      const float* th = &thS[b*52 + (lane>>5)*25];
      const float* tp = &tl[row*66 + (lane>>5)*25];
      float mix = 0.f;
      #pragma unroll 5
      for (int c=0;c<25;c++) mix = fmaf(th[c], tp[c], mix);
      mix += __shfl_xor(mix, 32);
      if (lane < 32 && v < 30000)
        local -= logf(mix + 1e-6f) * bows[b*30000 + v];
    }
    __syncthreads();
  }
  for (int o=1;o<64;o<<=1) local += __shfl_xor(local, o);
  if (lane==0) atomicAdd(acc+3, local);
}

// ---------------- finalize ----------------
__global__ void k_final(const float* __restrict__ acc, const int* __restrict__ nd,
                        float* __restrict__ out){
  float coeff = (float)(*nd) / 128.0f;
  float nll = acc[3]*coeff;
  float klth = acc[2]*coeff;
  out[0] = nll + acc[0] + acc[1] + klth;
  out[1] = nll;
  out[2] = acc[0];
  out[3] = acc[1];
  out[4] = klth;
}

extern "C" void kernel_launch(void* const* d_in, const int* in_sizes, int n_in,
                              void* d_out, int out_size, void* d_ws, size_t ws_size,
                              hipStream_t stream) {
  (void)in_sizes; (void)n_in; (void)out_size; (void)ws_size;
  const float* bows  = (const float*)d_in[0];
  const float* nb    = (const float*)d_in[1];
  const int*   times = (const int*)d_in[2];
  const float* rnn   = (const float*)d_in[3];
  const int*   ndocs = (const int*)d_in[4];
  const float* eps_a = (const float*)d_in[5];
  const float* eps_e = (const float*)d_in[6];
  const float* eps_t = (const float*)d_in[7];
  const float* rho   = (const float*)d_in[8];
  const float* mqa   = (const float*)d_in[9];
  const float* lqa   = (const float*)d_in[10];
  const float* W1    = (const float*)d_in[11];
  const float* b1    = (const float*)d_in[12];
  const float* W2    = (const float*)d_in[13];
  const float* b2    = (const float*)d_in[14];
  const float* Wmu_t = (const float*)d_in[15];
  const float* bmu_t = (const float*)d_in[16];
  const float* Wls_t = (const float*)d_in[17];
  const float* bls_t = (const float*)d_in[18];
  const float* Wmap  = (const float*)d_in[19];
  const float* bmap  = (const float*)d_in[20];
  const float* Wih   = (const float*)d_in[21];
  const float* Whh   = (const float*)d_in[22];
  const float* bih   = (const float*)d_in[23];
  const float* bhh   = (const float*)d_in[24];
  const float* Wmu_e = (const float*)d_in[25];
  const float* bmu_e = (const float*)d_in[26];
  const float* Wls_e = (const float*)d_in[27];
  const float* bls_e = (const float*)d_in[28];
  float* out = (float*)d_out;

  float* w      = (float*)d_ws;
  float* acc    = w;                        // 8
  unsigned short* rho_f   = (unsigned short*)(w + 8);           // 4,569,600 f
  unsigned short* alpha_f = (unsigned short*)(w + 8 + 4569600); // 583,680 f
  float* alphas = w + 8 + 4569600 + 583680; // 900000
  float* im     = alphas + 900000;          // 12000
  float* outA   = im + 12000;               // 12000
  float* outB   = outA + 12000;             // 12000
  float* pre    = outB + 12000;             // 48000
  float* etas   = pre + 48000;              // 3000
  float* h1     = etas + 3000;              // 102400
  float* h2     = h1 + 102400;              // 102400
  float* muth   = h2 + 102400;              // 6400
  float* lsth   = muth + 6400;              // 6400
  float* theta  = lsth + 6400;              // 6400
  float* Mp     = theta + 6400;             // 705000
  float* Sp     = Mp + 705000;              // 705000
  float* Mg     = Sp + 705000;              // 3000
  float* iSg    = Mg + 3000;                // 3000
  __half* whhH  = (__half*)(iSg + 3000);    // 480000 halves
  __half* wihH  = whhH + 480000;            // 480000 halves
  float* pre1   = (float*)(wihH + 480000);  // 48000
  float* pre2   = pre1 + 48000;             // 48000
  float* outC   = pre2 + 48000;             // 12000
  int*   flags  = (int*)(outC + 12000);     // 128 ints

  k_zero<<<1,128,0,stream>>>(acc, flags);
  k_alphas<<<3516,256,0,stream>>>(mqa, lqa, eps_a, alphas);
  k_klalpha<<<3516,256,0,stream>>>(mqa, lqa, alphas, acc);
  k_prep_rho<<<4465,256,0,stream>>>(rho, rho_f);
  k_prep_alpha<<<570,256,0,stream>>>(alphas, alpha_f);
  k_prep_w16<<<1875,256,0,stream>>>(Whh, Wih, whhH, wihH);
  k_iminit<<<47,256,0,stream>>>(im, bmap);
  k_imgemm<<<dim3(7,60),256,0,stream>>>(rnn, Wmap, im);

  // layer-0 pre-gates on the fully-known inp_map; layers 1/2 pregates are pipelined
  k_pregates<<<dim3(60,4),256,0,stream>>>(im, Wih, bih, bhh, pre);
  k_lstm_pipe<<<5,768,0,stream>>>(pre, whhH, wihH, bih, bhh,
                                  outA, outB, outC, pre1, pre2, flags);
  const float* lstm_out = outC;

  k_eta<<<1,256,0,stream>>>(lstm_out, Wmu_e, bmu_e, Wls_e, bls_e, eps_e, etas, acc);
  k_h1init<<<400,256,0,stream>>>(h1, b1);
  k_h1gemm<<<dim3(13,32),256,0,stream>>>(nb, times, etas, W1, h1);
  k_h2<<<dim3(4,13),256,0,stream>>>(h1, W2, b2, h2);
  k_muls<<<128,128,0,stream>>>(h2, Wmu_t, bmu_t, Wls_t, bls_t, muth, lsth);
  k_theta<<<128,64,0,stream>>>(muth, lsth, etas, times, eps_t, theta, acc);
  k_mf1<<<dim3(NVB,4),256,0,stream>>>(rho_f, alpha_f, Mp, Sp);
  k_msred<<<3000,256,0,stream>>>(Mp, Sp, Mg, iSg);
  k_mf2<<<dim3(NVB,4),256,0,stream>>>(rho_f, alpha_f, Mg, iSg, theta, times, bows, acc);
  k_final<<<1,1,0,stream>>>(acc, ndocs, out);
}

// Round 2
// 1614.555 us; speedup vs baseline: 2.0250x; 1.4855x over previous
//
#include <hip/hip_runtime.h>
#include <hip/hip_fp16.h>
#include <math.h>

#define TID ((int)threadIdx.x)

// dims: V=30000 K=50 E=300 T=60 B=128 TH=800 H=200 L=3
// mf2 tiling: NVB=235 v-blocks of 128 rows; mega-mf1: NVB2=79 v-blocks of 384 rows
#define NVB 235
#define NVB2 79

static __device__ __forceinline__ float sigf(float x){ return 1.f/(1.f+expf(-x)); }

static __device__ __forceinline__ unsigned short f2bf(float f){
  unsigned u = __float_as_uint(f);
  unsigned r = (u + 0x7FFFu + ((u>>16)&1u)) >> 16;
  return (unsigned short)r;
}

typedef short v8ss __attribute__((ext_vector_type(8)));
typedef float v16f __attribute__((ext_vector_type(16)));
union I4BF { int4 i; v8ss s; };
union U16B { int4 i; __half2 h2[4]; };

#define REP25(M) M(0) M(1) M(2) M(3) M(4) M(5) M(6) M(7) M(8) M(9) M(10) M(11) \
                 M(12) M(13) M(14) M(15) M(16) M(17) M(18) M(19) M(20) M(21) M(22) M(23) M(24)

#define DECLW(n) int4 w##n = wrow[n];
#define DOTW(n) { U16B u; u.i = w##n; \
    float4 hA = hs4[2*(n)], hB = hs4[2*(n)+1]; \
    float2 q0=__half22float2(u.h2[0]), q1=__half22float2(u.h2[1]); \
    float2 q2=__half22float2(u.h2[2]), q3=__half22float2(u.h2[3]); \
    a0=fmaf(q0.x,hA.x,a0); a1=fmaf(q0.y,hA.y,a1); \
    a2=fmaf(q1.x,hA.z,a2); a3=fmaf(q1.y,hA.w,a3); \
    a0=fmaf(q2.x,hB.x,a0); a1=fmaf(q2.y,hB.y,a1); \
    a2=fmaf(q3.x,hB.z,a2); a3=fmaf(q3.y,hB.w,a3); }

// ---------------- init ----------------
__global__ void k_zero(float* acc, int* flags){
  if (TID<8) acc[TID]=0.f;
  if (TID<160) flags[TID]=0;
}

// ---------------- alphas + kl_alpha ----------------
__global__ void k_alphas(const float* __restrict__ mqa, const float* __restrict__ lqa,
                         const float* __restrict__ eps, float* __restrict__ alphas){
  int i = blockIdx.x*256+TID; if (i>=900000) return;
  int t = i/15000, r = i%15000, k = r/300, e = r%300;
  int src = k*18000 + t*300 + e;
  float mu = mqa[src], ls = lqa[src];
  alphas[i] = mu + eps[i]*expf(0.5f*ls);
}

__global__ void k_klalpha(const float* __restrict__ mqa, const float* __restrict__ lqa,
                          const float* __restrict__ alphas, float* acc){
  __shared__ float red[256];
  int i = blockIdx.x*256+TID;
  float term = 0.f;
  if (i<900000){
    int t = i/15000, r = i%15000, k = r/300, e = r%300;
    int src = k*18000 + t*300 + e;
    float mu = mqa[src], ls = lqa[src];
    if (t==0){
      term = (expf(ls)+mu*mu)*(1.0f/(1.0f+1e-6f)) - 1.f - ls;
    } else {
      float d = mu - alphas[i-15000];
      term = (expf(ls)+d*d)*(1.0f/(0.005f+1e-6f)) - 1.f + logf(0.005f) - ls;
    }
  }
  red[TID]=term; __syncthreads();
  for (int s=128;s>0;s>>=1){ if (TID<s) red[TID]+=red[TID+s]; __syncthreads(); }
  if (TID==0) atomicAdd(acc+0, 0.5f*red[0]);
}

// ---------------- bf16 fragment prep for beta GEMM ----------------
__global__ void k_prep_rho(const float* __restrict__ rho, unsigned short* __restrict__ rho_f){
  int tid = blockIdx.x*256+TID;
  if (tid >= 940*19*64) return;
  int lane = tid & 63;
  int F = tid >> 6;
  int kstep = F % 19;
  int r32 = F / 19;
  int v = r32*32 + (lane & 31);
  int e0 = kstep*16 + ((lane>>5)<<3);
  unsigned short u[8];
  #pragma unroll
  for (int j=0;j<8;j++){
    int e = e0 + j;
    float val = (v < 30000 && e < 300) ? rho[v*300 + e] : 0.f;
    u[j] = f2bf(val);
  }
  int4 o;
  o.x = (int)u[0] | ((int)u[1]<<16);
  o.y = (int)u[2] | ((int)u[3]<<16);
  o.z = (int)u[4] | ((int)u[5]<<16);
  o.w = (int)u[6] | ((int)u[7]<<16);
  ((int4*)rho_f)[tid] = o;
}

__global__ void k_prep_alpha(const float* __restrict__ alphas, unsigned short* __restrict__ alpha_f){
  int tid = blockIdx.x*256+TID;
  if (tid >= 60*2*19*64) return;
  int lane = tid & 63;
  int F = tid >> 6;
  int kstep = F % 19;
  int tn = F / 19;
  int nt = tn % 2, t = tn / 2;
  int k = nt*32 + (lane & 31);
  int e0 = kstep*16 + ((lane>>5)<<3);
  unsigned short u[8];
  #pragma unroll
  for (int j=0;j<8;j++){
    int e = e0 + j;
    float val = (k < 50 && e < 300) ? alphas[t*15000 + k*300 + e] : 0.f;
    u[j] = f2bf(val);
  }
  int4 o;
  o.x = (int)u[0] | ((int)u[1]<<16);
  o.y = (int)u[2] | ((int)u[3]<<16);
  o.z = (int)u[4] | ((int)u[5]<<16);
  o.w = (int)u[6] | ((int)u[7]<<16);
  ((int4*)alpha_f)[tid] = o;
}

// ---------------- Whh + Wih f32 -> f16 (3 layers, 480000 elems each) ----------------
__global__ void k_prep_w16(const float* __restrict__ Whh, const float* __restrict__ Wih,
                           __half* __restrict__ WhhH, __half* __restrict__ WihH){
  int i = blockIdx.x*256+TID;
  if (i<480000){
    WhhH[i] = __float2half_rn(Whh[i]);
    WihH[i] = __float2half_rn(Wih[i]);
  }
}

// ---------------- inp_map = rnn_inp @ Wmap.T + bmap ----------------
__global__ void k_iminit(float* __restrict__ im, const float* __restrict__ bmap){
  int i = blockIdx.x*256+TID; if (i<12000) im[i] = bmap[i%200];
}

__global__ __launch_bounds__(256,2) void k_imgemm(const float* __restrict__ rnn,
        const float* __restrict__ Wmap, float* __restrict__ im){
  __shared__ __align__(16) float Ws[32*500];
  __shared__ __align__(16) float rnS[500];
  int hb = blockIdx.x;       // 0..6
  int kb = blockIdx.y;       // 0..59
  int h0 = hb*32;
  int nh = (h0+32<=200)?32:(200-h0);
  const int kbase = kb*500;
  for (int i=TID; i<nh*125; i+=256){
    int h = i/125, q = i%125;
    *reinterpret_cast<float4*>(&Ws[h*500 + q*4]) =
      *reinterpret_cast<const float4*>(&Wmap[(h0+h)*30000 + kbase + q*4]);
  }
  int h = TID>>3, sub = TID&7;
  bool act = (h < nh);
  __syncthreads();
  for (int t=0;t<60;t++){
    if (TID<125)
      *reinterpret_cast<float4*>(&rnS[TID*4]) =
        *reinterpret_cast<const float4*>(&rnn[t*30000 + kbase + TID*4]);
    __syncthreads();
    float a = 0.f;
    if (act){
      const float2* wp = reinterpret_cast<const float2*>(&Ws[h*500]);
      const float2* rp = reinterpret_cast<const float2*>(rnS);
      for (int k2=sub;k2<250;k2+=8){
        float2 wv=wp[k2], rv=rp[k2];
        a = fmaf(wv.x,rv.x,a); a = fmaf(wv.y,rv.y,a);
      }
    }
    a += __shfl_down(a,4); a += __shfl_down(a,2); a += __shfl_down(a,1);
    if (act && sub==0) atomicAdd(&im[t*200 + h0 + h], a);
    __syncthreads();
  }
}

// ---------------- LSTM pre-gates (layer 0 only; input fully known) ----------------
__global__ void k_pregates(const float* __restrict__ x, const float* __restrict__ Wih,
                           const float* __restrict__ bih, const float* __restrict__ bhh,
                           float* __restrict__ pre){
  __shared__ float xS[200];
  int t = blockIdx.x;
  if (TID<200) xS[TID] = x[t*200+TID];
  __syncthreads();
  int r = blockIdx.y*256 + TID;
  if (r>=800) return;
  float a = bih[r] + bhh[r];
  const float* wp = Wih + r*200;
  #pragma unroll 4
  for (int c=0;c<200;c++) a = fmaf(wp[c], xS[c], a);
  pre[t*800+r] = a;
}

// ---------------- h1 init ----------------
__global__ void k_h1init(float* __restrict__ h1, const float* __restrict__ b1){
  int i = blockIdx.x*256+TID; if (i<102400) h1[i] = b1[i%800];
}

// ================= MEGA KERNEL: pipe (6 blocks) + mf1 (316) + h1-main (160) =====
// All device funcs overlay one 53KB LDS buffer. Cross-block handoff per timestep
// via agent-scope release/acquire flags.

static __device__ __forceinline__ void pipe_wait(int* flag, int val){
  if (TID==0){
    while (__hip_atomic_load(flag, __ATOMIC_ACQUIRE, __HIP_MEMORY_SCOPE_AGENT) < val)
      __builtin_amdgcn_s_sleep(2);
  }
  __syncthreads();
}

static __device__ __forceinline__ void pipe_post(int* flag, int val){
  if (TID==0)
    __hip_atomic_store(flag, val, __ATOMIC_RELEASE, __HIP_MEMORY_SCOPE_AGENT);
}

// recurrent cell chain: weights in 25 named int4 regs (f16), rows 768-799 via LDS tail
static __device__ void lstm_rec(char* sm, const float* __restrict__ pre,
    const __half* __restrict__ WhhH, float* __restrict__ out,
    int* inFlag, int* outFlag)
{
  float* hsF = (float*)sm;              // 200 f
  float* gsh = (float*)(sm + 800);      // 800 f
  __half* wtH = (__half*)(sm + 4000);   // 6400 h
  for (int i=TID;i<6400;i+=768) wtH[i] = WhhH[768*200 + i];
  const int4* wrow = reinterpret_cast<const int4*>(WhhH + TID*200);
  REP25(DECLW)
  float c_reg = 0.f;
  if (TID<200) hsF[TID]=0.f;
  int j = TID - 512;
  int trow = (j>=0) ? (j>>3) : 0;
  int tseg = (j>=0) ? (j&7)*25 : 0;
  __syncthreads();
  for (int t=0;t<60;t++){
    if (inFlag) pipe_wait(inFlag, t+1);
    float p = pre[t*800+TID];          // latency hides under the h-dot below
    float a0=0.f,a1=0.f,a2=0.f,a3=0.f;
    const float4* hs4 = reinterpret_cast<const float4*>(hsF);
    REP25(DOTW)
    gsh[TID] = a0+a1+a2+a3 + p;
    if (j>=0){
      float pa = 0.f;
      const __half* wt = &wtH[trow*200 + tseg];
      const float* hp = &hsF[tseg];
      #pragma unroll
      for (int c2=0;c2<25;c2++) pa = fmaf(__half2float(wt[c2]), hp[c2], pa);
      pa += __shfl_down(pa,4); pa += __shfl_down(pa,2); pa += __shfl_down(pa,1);
      if ((j&7)==0) gsh[768+trow] = pa + pre[t*800+768+trow];
    }
    __syncthreads();
    if (TID<200){
      float ii=gsh[TID], ff=gsh[200+TID], gg=gsh[400+TID], oo=gsh[600+TID];
      float c = sigf(ff)*c_reg + sigf(ii)*tanhf(gg);
      c_reg = c;
      float h = sigf(oo)*tanhf(c);
      hsF[TID]=h;
      out[t*200+TID]=h;
    }
    __syncthreads();
    if (outFlag) pipe_post(outFlag, t+1);
  }
}

// input-gemv stage: pre_l[t] = Wih_l @ out_{l-1}[t] + bih + bhh
static __device__ void lstm_gemv(char* sm, const float* __restrict__ xIn,
    const __half* __restrict__ WH, const float* __restrict__ bih,
    const float* __restrict__ bhh, float* __restrict__ preOut,
    int* inFlag, int* outFlag)
{
  float* xS = (float*)sm;               // 200 f
  __half* wtG = (__half*)(sm + 800);    // 6400 h
  for (int i=TID;i<6400;i+=768) wtG[i] = WH[768*200 + i];
  const int4* wrow = reinterpret_cast<const int4*>(WH + TID*200);
  REP25(DECLW)
  float bb = bih[TID] + bhh[TID];
  int j = TID - 512;
  int trow = (j>=0) ? (j>>3) : 0;
  int tseg = (j>=0) ? (j&7)*25 : 0;
  float bbT = 0.f;
  if (j>=0 && (j&7)==0) bbT = bih[768+trow] + bhh[768+trow];
  for (int t=0;t<60;t++){
    pipe_wait(inFlag, t+1);
    if (TID<200) xS[TID] = xIn[t*200+TID];
    __syncthreads();
    float a0=0.f,a1=0.f,a2=0.f,a3=0.f;
    const float4* hs4 = reinterpret_cast<const float4*>(xS);
    REP25(DOTW)
    preOut[t*800+TID] = a0+a1+a2+a3 + bb;
    if (j>=0){
      float pa = 0.f;
      const __half* wt = &wtG[trow*200 + tseg];
      const float* hp = &xS[tseg];
      #pragma unroll
      for (int c2=0;c2<25;c2++) pa = fmaf(__half2float(wt[c2]), hp[c2], pa);
      pa += __shfl_down(pa,4); pa += __shfl_down(pa,2); pa += __shfl_down(pa,1);
      if ((j&7)==0) preOut[t*800+768+trow] = pa + bbT;
    }
    __syncthreads();
    pipe_post(outFlag, t+1);
  }
}

// eta chain as 6th pipeline stage (guarded to 256 active lanes; waves 4-11 idle at barriers)
static __device__ void eta_stage(char* sm, const float* __restrict__ outF,
    const float* __restrict__ Wmu, const float* __restrict__ bmu,
    const float* __restrict__ Wls, const float* __restrict__ bls,
    const float* __restrict__ eps, float* __restrict__ etas, float* acc,
    int* inFlag)
{
  __half* wS = (__half*)sm;                 // 100*254 h = 50800 B
  float* inp = (float*)(sm + 50816);        // 256 f
  float* pt  = (float*)(sm + 51840);        // 200 f
  float* muS = (float*)(sm + 52640);        // 64 f
  float* lsS = (float*)(sm + 52896);        // 64 f
  for (int i=TID;i<12500;i+=768) wS[(i/250)*254 + (i%250)] = __float2half_rn(Wmu[i]);
  for (int i=TID;i<12500;i+=768) wS[(50+i/250)*254 + (i%250)] = __float2half_rn(Wls[i]);
  if (TID<50) inp[200+TID]=0.f;
  const float LOGD = logf(0.005f);
  float kacc = 0.f;
  __syncthreads();
  for (int t=0;t<60;t++){
    pipe_wait(inFlag, t+1);
    if (TID<200) inp[TID] = outF[t*200+TID];
    __syncthreads();
    if (TID<200){
      int rr = TID%100, hf = TID/100;
      const __half* wp = &wS[rr*254 + hf*125];
      const float* ip = &inp[hf*125];
      float s=0.f;
      for (int c=0;c<125;c++) s = fmaf(__half2float(wp[c]), ip[c], s);
      pt[TID]=s;
    }
    __syncthreads();
    if (TID<100){
      float v = pt[TID]+pt[TID+100];
      if (TID<50) muS[TID] = v + bmu[TID];
      else lsS[TID-50] = v + bls[TID-50];
    }
    __syncthreads();
    if (TID<64){
      float term=0.f;
      if (TID<50){
        float mu=muS[TID], ls=lsS[TID], ep=inp[200+TID];
        if (t==0) term = (expf(ls)+mu*mu)*(1.0f/(1.0f+1e-6f)) - 1.f - ls;
        else { float d=mu-ep; term = (expf(ls)+d*d)*(1.0f/(0.005f+1e-6f)) - 1.f + LOGD - ls; }
        float et = mu + eps[t*50+TID]*expf(0.5f*ls);
        etas[t*50+TID]=et;
        inp[200+TID]=et;
      }
      for (int o=32;o>0;o>>=1) term += __shfl_down(term,o);
      if (TID==0) kacc += 0.5f*term;
    }
    __syncthreads();
  }
  if (TID==0) atomicAdd(acc+1, kacc);
}

// MFMA beta pass 1, 768-thread port: 12 waves = 384 v-rows per block
static __device__ void mf1_block(char* sm, int vb, int tg,
    const unsigned short* __restrict__ rho_f, const unsigned short* __restrict__ alpha_f,
    float* __restrict__ Mp, float* __restrict__ Sp)
{
  float* redM = (float*)sm;            // 12*64 f
  float* redS = (float*)(sm + 3072);   // 12*64 f
  int wid = TID>>6, lane = TID&63;
  int r32 = vb*12 + wid;               // 0..947 (940 valid)
  bool valid = (r32 < 940);
  int4 zi; zi.x=0; zi.y=0; zi.z=0; zi.w=0;
  const int4* ap = ((const int4*)rho_f) + (r32*19)*64 + lane;
  int4 a[19];
  #pragma unroll
  for (int ks=0;ks<19;ks++) a[ks] = valid ? ap[ks*64] : zi;
  int rowbase = vb*384 + wid*32 + ((lane>>5)<<2);
  for (int t = tg*15; t < tg*15+15; t++){
    v16f acc0, acc1;
    #pragma unroll
    for (int i=0;i<16;i++){ acc0[i]=0.f; acc1[i]=0.f; }
    const int4* bp = ((const int4*)alpha_f) + (t*38)*64 + lane;
    #pragma unroll
    for (int ks=0;ks<19;ks++){
      I4BF av, b0, b1;
      av.i = a[ks];
      b0.i = bp[ks*64];
      b1.i = bp[(19+ks)*64];
      acc0 = __builtin_amdgcn_mfma_f32_32x32x16_bf16(av.s, b0.s, acc0, 0,0,0);
      acc1 = __builtin_amdgcn_mfma_f32_32x32x16_bf16(av.s, b1.s, acc1, 0,0,0);
    }
    float m0=-INFINITY, m1=-INFINITY;
    #pragma unroll
    for (int r=0;r<16;r++){
      int v = rowbase + (r&3) + ((r>>2)<<3);
      if (v < 30000){ m0 = fmaxf(m0, acc0[r]); m1 = fmaxf(m1, acc1[r]); }
    }
    m0 = fmaxf(m0, __shfl_xor(m0, 32));
    m1 = fmaxf(m1, __shfl_xor(m1, 32));
    float s0=0.f, s1=0.f;
    #pragma unroll
    for (int r=0;r<16;r++){
      int v = rowbase + (r&3) + ((r>>2)<<3);
      if (v < 30000){ s0 += expf(acc0[r]-m0); s1 += expf(acc1[r]-m1); }
    }
    s0 += __shfl_xor(s0, 32);
    s1 += __shfl_xor(s1, 32);
    if (lane < 32){
      redM[wid*64+lane] = m0; redM[wid*64+lane+32] = m1;
      redS[wid*64+lane] = s0; redS[wid*64+lane+32] = s1;
    }
    __syncthreads();
    if (TID < 50){
      float M = redM[TID];
      #pragma unroll
      for (int w2=1; w2<12; w2++) M = fmaxf(M, redM[w2*64+TID]);
      float S = 0.f;
      #pragma unroll
      for (int w2=0; w2<12; w2++){
        float mw = redM[w2*64+TID];
        if (mw > -INFINITY) S += redS[w2*64+TID] * expf(mw - M);
      }
      Mp[(t*50+TID)*NVB2 + vb] = M;
      Sp[(t*50+TID)*NVB2 + vb] = S;
    }
    __syncthreads();
  }
}

// h1 main GEMM (k<30000 only), 768-thread port: 3 rt-tiles share one A-tile
static __device__ void h1_block(char* sm, int rtg, int sp,
    const float* __restrict__ nb, const float* __restrict__ W1,
    float* __restrict__ h1)
{
  float* As = (float*)sm;               // 16*132 f
  float* WsAll = (float*)(sm + 8448);   // 3 * 16*68 f
  int sub = TID>>8, l = TID&255;
  int rt = rtg*3 + sub;                 // 0..14 (rows >=800 masked)
  float* Ws = WsAll + sub*(16*68);
  int kbeg = sp*940;
  int kend = kbeg+940; if (kend>30000) kend=30000;
  int b0 = (l%32)*4, r0 = (l/32)*8;
  float acc[32];
  #pragma unroll
  for (int jj=0;jj<32;jj++) acc[jj]=0.f;
  for (int kb=kbeg; kb<kend; kb+=16){
    __syncthreads();
    for (int i=TID;i<2048;i+=768){
      int b=i>>4, kk=i&15, kg=kb+kk;
      As[kk*132+b] = (kg<kend) ? nb[b*30000+kg] : 0.f;
    }
    for (int i=l;i<1024;i+=256){
      int r=i>>4, kk=i&15, kg=kb+kk, rg=rt*64+r;
      Ws[kk*68+r] = (kg<kend && rg<800) ? W1[rg*30050+kg] : 0.f;
    }
    __syncthreads();
    #pragma unroll
    for (int kk=0;kk<16;kk++){
      float4 a4 = *reinterpret_cast<const float4*>(&As[kk*132+b0]);
      float4 w4 = *reinterpret_cast<const float4*>(&Ws[kk*68+r0]);
      float4 w5 = *reinterpret_cast<const float4*>(&Ws[kk*68+r0+4]);
      float aa[4]={a4.x,a4.y,a4.z,a4.w};
      float ww[8]={w4.x,w4.y,w4.z,w4.w,w5.x,w5.y,w5.z,w5.w};
      #pragma unroll
      for (int j=0;j<4;j++)
        #pragma unroll
        for (int i2=0;i2<8;i2++) acc[j*8+i2] = fmaf(aa[j], ww[i2], acc[j*8+i2]);
    }
  }
  #pragma unroll
  for (int j=0;j<4;j++){
    int b=b0+j;
    #pragma unroll
    for (int i2=0;i2<8;i2++){
      int rg = rt*64+r0+i2;
      if (rg<800) atomicAdd(&h1[b*800+rg], acc[j*8+i2]);
    }
  }
}

__global__ __launch_bounds__(768,3) void k_mega(
    const float* __restrict__ pre0, const __half* __restrict__ WhhH,
    const __half* __restrict__ WihH, const float* __restrict__ bih,
    const float* __restrict__ bhh, float* __restrict__ out0,
    float* __restrict__ out1, float* __restrict__ out2,
    float* __restrict__ pre1, float* __restrict__ pre2, int* __restrict__ flags,
    const float* __restrict__ Wmu_e, const float* __restrict__ bmu_e,
    const float* __restrict__ Wls_e, const float* __restrict__ bls_e,
    const float* __restrict__ eps_e, float* __restrict__ etas, float* acc,
    const unsigned short* __restrict__ rho_f, const unsigned short* __restrict__ alpha_f,
    float* __restrict__ Mp, float* __restrict__ Sp,
    const float* __restrict__ nb, const float* __restrict__ W1, float* __restrict__ h1)
{
  __shared__ __align__(16) unsigned char smem[53248];
  char* sm = (char*)smem;
  int bid = blockIdx.x;
  if (bid==0)      lstm_rec (sm, pre0, WhhH,        out0, nullptr,   flags+0);
  else if (bid==1) lstm_gemv(sm, out0, WihH+160000, bih+800,  bhh+800,  pre1, flags+0,  flags+32);
  else if (bid==2) lstm_rec (sm, pre1, WhhH+160000, out1, flags+32, flags+64);
  else if (bid==3) lstm_gemv(sm, out1, WihH+320000, bih+1600, bhh+1600, pre2, flags+64, flags+96);
  else if (bid==4) lstm_rec (sm, pre2, WhhH+320000, out2, flags+96, flags+128);
  else if (bid==5) eta_stage(sm, out2, Wmu_e, bmu_e, Wls_e, bls_e, eps_e, etas, acc, flags+128);
  else if (bid<322){ int i=bid-6;   mf1_block(sm, i>>2, i&3, rho_f, alpha_f, Mp, Sp); }
  else             { int j=bid-322; h1_block(sm, j>>5, j&31, nb, W1, h1); }
}

// ---------------- eta columns of h1 (tiny, after mega) ----------------
__global__ void k_h1eta(const float* __restrict__ etas, const int* __restrict__ times,
                        const float* __restrict__ W1, float* __restrict__ h1){
  __shared__ float eS[50];
  int b = blockIdx.x;
  if (TID<50) eS[TID] = etas[times[b]*50 + TID];
  __syncthreads();
  for (int r=TID; r<800; r+=256){
    const float* wp = W1 + r*30050 + 30000;
    float a2=0.f;
    #pragma unroll 10
    for (int c=0;c<50;c++) a2 = fmaf(wp[c], eS[c], a2);
    h1[b*800+r] += a2;
  }
}

// ---------------- reduce partials -> M, 1/S ----------------
__global__ void k_msred(const float* __restrict__ Mp, const float* __restrict__ Sp,
                        float* __restrict__ Mg, float* __restrict__ iSg){
  __shared__ float red[256];
  int row = blockIdx.x;
  float m = (TID<NVB2) ? Mp[row*NVB2+TID] : -INFINITY;
  red[TID]=m; __syncthreads();
  for (int s=128;s>0;s>>=1){ if (TID<s) red[TID]=fmaxf(red[TID],red[TID+s]); __syncthreads(); }
  float M = red[0]; __syncthreads();
  float sv = (TID<NVB2) ? Sp[row*NVB2+TID]*expf(m-M) : 0.f;
  red[TID]=sv; __syncthreads();
  for (int s=128;s>0;s>>=1){ if (TID<s) red[TID]+=red[TID+s]; __syncthreads(); }
  if (TID==0){ Mg[row]=M; iSg[row]=1.f/red[0]; }
}

// ---------------- h2 = relu(relu(h1) @ W2.T + b2), tiled 32x64 ----------------
__global__ __launch_bounds__(256) void k_h2(const float* __restrict__ h1,
        const float* __restrict__ W2, const float* __restrict__ b2,
        float* __restrict__ h2){
  __shared__ __align__(16) float As[16*33];
  __shared__ __align__(16) float Ws[16*68];
  int bt = blockIdx.x;  // 0..3  (32 docs)
  int rt = blockIdx.y;  // 0..12 (64 rows)
  int b0 = (TID%16)*2, r0 = (TID/16)*4;
  float acc[8] = {0,0,0,0,0,0,0,0};
  for (int kb=0; kb<800; kb+=16){
    __syncthreads();
    for (int i=TID;i<512;i+=256){
      int b=i>>4, k=i&15;
      As[k*33+b] = fmaxf(h1[(bt*32+b)*800 + kb + k], 0.f);
    }
    for (int i=TID;i<1024;i+=256){
      int r=i>>4, k=i&15; int rg = rt*64+r;
      Ws[k*68+r] = (rg<800) ? W2[rg*800 + kb + k] : 0.f;
    }
    __syncthreads();
    #pragma unroll
    for (int k=0;k<16;k++){
      float a0=As[k*33+b0], a1=As[k*33+b0+1];
      float4 w4 = *reinterpret_cast<const float4*>(&Ws[k*68+r0]);
      acc[0]=fmaf(a0,w4.x,acc[0]); acc[1]=fmaf(a0,w4.y,acc[1]);
      acc[2]=fmaf(a0,w4.z,acc[2]); acc[3]=fmaf(a0,w4.w,acc[3]);
      acc[4]=fmaf(a1,w4.x,acc[4]); acc[5]=fmaf(a1,w4.y,acc[5]);
      acc[6]=fmaf(a1,w4.z,acc[6]); acc[7]=fmaf(a1,w4.w,acc[7]);
    }
  }
  #pragma unroll
  for (int jj=0;jj<2;jj++){
    int b = bt*32 + b0 + jj;
    #pragma unroll
    for (int i2=0;i2<4;i2++){
      int rg = rt*64 + r0 + i2;
      if (rg<800) h2[b*800+rg] = fmaxf(acc[jj*4+i2] + b2[rg], 0.f);
    }
  }
}

// ---------------- mu_th / ls_th ----------------
__global__ void k_muls(const float* __restrict__ h2, const float* __restrict__ Wmu,
                       const float* __restrict__ bmu, const float* __restrict__ Wls,
                       const float* __restrict__ bls, float* __restrict__ muth,
                       float* __restrict__ lsth){
  __shared__ float hS[800];
  int b = blockIdx.x;
  for (int i=TID;i<800;i+=128) hS[i] = h2[b*800+i];
  __syncthreads();
  if (TID<50){
    float a = bmu[TID];
    const float* wp = Wmu + TID*800;
    #pragma unroll 4
    for (int c=0;c<800;c++) a = fmaf(wp[c], hS[c], a);
    muth[b*50+TID]=a;
  } else if (TID>=64 && TID<114){
    int r = TID-64;
    float a = bls[r];
    const float* wp = Wls + r*800;
    #pragma unroll 4
    for (int c=0;c<800;c++) a = fmaf(wp[c], hS[c], a);
    lsth[b*50+r]=a;
  }
}

// ---------------- theta + kl_theta ----------------
__global__ void k_theta(const float* __restrict__ muth, const float* __restrict__ lsth,
                        const float* __restrict__ etas, const int* __restrict__ times,
                        const float* __restrict__ epsth, float* __restrict__ theta,
                        float* acc){
  int b = blockIdx.x, k = TID;
  bool a = k<50;
  int tb = times[b];
  float mu=0.f, ls=0.f, etd=0.f, z=-INFINITY;
  if (a){
    mu = muth[b*50+k]; ls = lsth[b*50+k]; etd = etas[tb*50+k];
    z = mu + epsth[b*50+k]*expf(0.5f*ls);
  }
  float m=z;
  for (int o=32;o>0;o>>=1) m = fmaxf(m, __shfl_xor(m,o));
  float e = a ? expf(z-m) : 0.f;
  float s = e;
  for (int o=32;o>0;o>>=1) s += __shfl_xor(s,o);
  if (a) theta[b*50+k] = e/s;
  float term = a ? ((expf(ls)+(mu-etd)*(mu-etd))*(1.0f/(1.0f+1e-6f)) - 1.f - ls) : 0.f;
  for (int o=32;o>0;o>>=1) term += __shfl_xor(term,o);
  if (TID==0) atomicAdd(acc+2, 0.5f*term);
}

// ---------------- MFMA beta pass 2: recompute, normalize, fuse nll ----------------
__global__ __launch_bounds__(256,2) void k_mf2(const unsigned short* __restrict__ rho_f,
        const unsigned short* __restrict__ alpha_f,
        const float* __restrict__ Mg, const float* __restrict__ iSg,
        const float* __restrict__ theta, const int* __restrict__ times,
        const float* __restrict__ bows, float* acc){
  __shared__ float thS[128*52];
  __shared__ float tileS[4][32*66];
  __shared__ int tS[128];
  __shared__ int cntS[64];
  int vb = blockIdx.x, tg = blockIdx.y;
  int wid = TID>>6, lane = TID&63;
  if (TID < 64) cntS[TID] = 0;
  __syncthreads();
  if (TID < 128){ int tv = times[TID]; tS[TID] = tv; atomicAdd(&cntS[tv], 1); }
  for (int i=TID; i<6400; i+=256){ int b=i/50, c=i%50; thS[b*52+c] = theta[i]; }
  int r32 = vb*4 + wid;
  const int4* ap = ((const int4*)rho_f) + (r32*19)*64 + lane;
  int4 a[19];
  #pragma unroll
  for (int ks=0;ks<19;ks++) a[ks] = ap[ks*64];
  __syncthreads();
  float local = 0.f;
  int rb32 = ((lane>>5)<<2);
  int c0 = lane&31, c1 = 32 + (lane&31);
  for (int t = tg*15; t < tg*15+15; t++){
    if (cntS[t] == 0) continue;
    v16f acc0, acc1;
    #pragma unroll
    for (int i=0;i<16;i++){ acc0[i]=0.f; acc1[i]=0.f; }
    const int4* bp = ((const int4*)alpha_f) + (t*38)*64 + lane;
    #pragma unroll
    for (int ks=0;ks<19;ks++){
      I4BF av, b0, b1;
      av.i = a[ks];
      b0.i = bp[ks*64];
      b1.i = bp[(19+ks)*64];
      acc0 = __builtin_amdgcn_mfma_f32_32x32x16_bf16(av.s, b0.s, acc0, 0,0,0);
      acc1 = __builtin_amdgcn_mfma_f32_32x32x16_bf16(av.s, b1.s, acc1, 0,0,0);
    }
    float M0 = Mg[t*50+c0], i0 = iSg[t*50+c0];
    float M1 = 0.f, i1 = 0.f;
    if (c1 < 50){ M1 = Mg[t*50+c1]; i1 = iSg[t*50+c1]; }
    float* tl = &tileS[wid][0];
    #pragma unroll
    for (int r=0;r<16;r++){
      int row = rb32 + (r&3) + ((r>>2)<<3);
      tl[row*66 + c0] = expf(acc0[r]-M0)*i0;
      if (c1 < 50) tl[row*66 + c1] = expf(acc1[r]-M1)*i1;
    }
    __syncthreads();
    for (int b=0;b<128;b++){
      if (tS[b] != t) continue;
      int row = lane&31;
      int v = vb*128 + wid*32 + row;
      const float* th = &thS[b*52 + (lane>>5)*25];
      const float* tp = &tl[row*66 + (lane>>5)*25];
      float mix = 0.f;
      #pragma unroll 5
      for (int c=0;c<25;c++) mix = fmaf(th[c], tp[c], mix);
      mix += __shfl_xor(mix, 32);
      if (lane < 32 && v < 30000)
        local -= logf(mix + 1e-6f) * bows[b*30000 + v];
    }
    __syncthreads();
  }
  for (int o=1;o<64;o<<=1) local += __shfl_xor(local, o);
  if (lane==0) atomicAdd(acc+3, local);
}

// ---------------- finalize ----------------
__global__ void k_final(const float* __restrict__ acc, const int* __restrict__ nd,
                        float* __restrict__ out){
  float coeff = (float)(*nd) / 128.0f;
  float nll = acc[3]*coeff;
  float klth = acc[2]*coeff;
  out[0] = nll + acc[0] + acc[1] + klth;
  out[1] = nll;
  out[2] = acc[0];
  out[3] = acc[1];
  out[4] = klth;
}

extern "C" void kernel_launch(void* const* d_in, const int* in_sizes, int n_in,
                              void* d_out, int out_size, void* d_ws, size_t ws_size,
                              hipStream_t stream) {
  (void)in_sizes; (void)n_in; (void)out_size; (void)ws_size;
  const float* bows  = (const float*)d_in[0];
  const float* nb    = (const float*)d_in[1];
  const int*   times = (const int*)d_in[2];
  const float* rnn   = (const float*)d_in[3];
  const int*   ndocs = (const int*)d_in[4];
  const float* eps_a = (const float*)d_in[5];
  const float* eps_e = (const float*)d_in[6];
  const float* eps_t = (const float*)d_in[7];
  const float* rho   = (const float*)d_in[8];
  const float* mqa   = (const float*)d_in[9];
  const float* lqa   = (const float*)d_in[10];
  const float* W1    = (const float*)d_in[11];
  const float* b1    = (const float*)d_in[12];
  const float* W2    = (const float*)d_in[13];
  const float* b2    = (const float*)d_in[14];
  const float* Wmu_t = (const float*)d_in[15];
  const float* bmu_t = (const float*)d_in[16];
  const float* Wls_t = (const float*)d_in[17];
  const float* bls_t = (const float*)d_in[18];
  const float* Wmap  = (const float*)d_in[19];
  const float* bmap  = (const float*)d_in[20];
  const float* Wih   = (const float*)d_in[21];
  const float* Whh   = (const float*)d_in[22];
  const float* bih   = (const float*)d_in[23];
  const float* bhh   = (const float*)d_in[24];
  const float* Wmu_e = (const float*)d_in[25];
  const float* bmu_e = (const float*)d_in[26];
  const float* Wls_e = (const float*)d_in[27];
  const float* bls_e = (const float*)d_in[28];
  float* out = (float*)d_out;

  float* p = (float*)d_ws;
  float* acc    = p; p += 8;
  unsigned short* rho_f   = (unsigned short*)p; p += 4572160;  // 940*19*64 int4
  unsigned short* alpha_f = (unsigned short*)p; p += 583680;   // 60*2*19*64 int4
  float* alphas = p; p += 900000;
  float* im     = p; p += 12000;
  float* out0   = p; p += 12000;
  float* out1   = p; p += 12000;
  float* out2   = p; p += 12000;
  float* pre0   = p; p += 48000;
  float* pre1   = p; p += 48000;
  float* pre2   = p; p += 48000;
  float* etas   = p; p += 3000;
  float* h1     = p; p += 102400;
  float* h2     = p; p += 102400;
  float* muth   = p; p += 6400;
  float* lsth   = p; p += 6400;
  float* theta  = p; p += 6400;
  float* Mp     = p; p += 3000*NVB2;
  float* Sp     = p; p += 3000*NVB2;
  float* Mg     = p; p += 3000;
  float* iSg    = p; p += 3000;
  __half* whhH  = (__half*)p; p += 240000;   // 480000 halves
  __half* wihH  = (__half*)p; p += 240000;   // 480000 halves
  int*   flags  = (int*)p; p += 256;

  k_zero<<<1,256,0,stream>>>(acc, flags);
  k_alphas<<<3516,256,0,stream>>>(mqa, lqa, eps_a, alphas);
  k_klalpha<<<3516,256,0,stream>>>(mqa, lqa, alphas, acc);
  k_prep_rho<<<4465,256,0,stream>>>(rho, rho_f);
  k_prep_alpha<<<570,256,0,stream>>>(alphas, alpha_f);
  k_prep_w16<<<1875,256,0,stream>>>(Whh, Wih, whhH, wihH);
  k_iminit<<<47,256,0,stream>>>(im, bmap);
  k_imgemm<<<dim3(7,60),256,0,stream>>>(rnn, Wmap, im);
  k_pregates<<<dim3(60,4),256,0,stream>>>(im, Wih, bih, bhh, pre0);
  k_h1init<<<400,256,0,stream>>>(h1, b1);

  // mega: 6 pipe blocks + 316 mf1 blocks + 160 h1-main blocks
  k_mega<<<482,768,0,stream>>>(pre0, whhH, wihH, bih, bhh, out0, out1, out2,
                               pre1, pre2, flags,
                               Wmu_e, bmu_e, Wls_e, bls_e, eps_e, etas, acc,
                               rho_f, alpha_f, Mp, Sp, nb, W1, h1);

  k_msred<<<3000,256,0,stream>>>(Mp, Sp, Mg, iSg);
  k_h1eta<<<128,256,0,stream>>>(etas, times, W1, h1);
  k_h2<<<dim3(4,13),256,0,stream>>>(h1, W2, b2, h2);
  k_muls<<<128,128,0,stream>>>(h2, Wmu_t, bmu_t, Wls_t, bls_t, muth, lsth);
  k_theta<<<128,64,0,stream>>>(muth, lsth, etas, times, eps_t, theta, acc);
  k_mf2<<<dim3(NVB,4),256,0,stream>>>(rho_f, alpha_f, Mg, iSg, theta, times, bows, acc);
  k_final<<<1,1,0,stream>>>(acc, ndocs, out);
}